// Round 1
// baseline (1415.225 us; speedup 1.0000x reference)
//
#include <hip/hip_runtime.h>
#include <math.h>

// Problem constants (fixed by the reference)
#define B_SZ    2
#define LSEQ    1024
#define DIM     1024
#define DSTATE  16
#define DCONV   4
#define DIN     2048          // d_inner
#define MROWS   (B_SZ * LSEQ) // 2048

// ---------------------------------------------------------------------------
// NT GEMM: C[m,n] = sum_k A[m,k] * B[n,k]   (A row-major [M,K], B row-major [N,K])
// EPI: 0 = plain store; 1 = softplus(acc + aux[n]); 2 = acc + aux[m*N+n]
// Tile 64x64, 256 threads, 4x4 per thread, BK=16.
// ---------------------------------------------------------------------------
#define BM 64
#define BN 64
#define BK 16

__device__ __forceinline__ float softplus_f(float x) {
    // stable: max(x,0) + log1p(exp(-|x|))
    return fmaxf(x, 0.0f) + log1pf(__expf(-fabsf(x)));
}

template <int EPI>
__global__ __launch_bounds__(256) void gemm_nt(
    const float* __restrict__ A, const float* __restrict__ Bm,
    float* __restrict__ C, int M, int N, int K,
    const float* __restrict__ aux)
{
    __shared__ float As[BK][BM + 4];
    __shared__ float Bs[BK][BN + 4];

    const int t   = threadIdx.x;
    const int tx  = t & 15;        // 0..15 -> col group
    const int ty  = t >> 4;        // 0..15 -> row group
    const int row0 = blockIdx.y * BM;
    const int col0 = blockIdx.x * BN;

    float acc[4][4] = {};

    for (int k0 = 0; k0 < K; k0 += BK) {
        #pragma unroll
        for (int i = 0; i < 4; ++i) {
            int idx = t + i * 256;      // 0..1023
            int r   = idx >> 4;         // 0..63
            int kk  = idx & 15;
            As[kk][r] = A[(size_t)(row0 + r) * K + k0 + kk];
            Bs[kk][r] = Bm[(size_t)(col0 + r) * K + k0 + kk];
        }
        __syncthreads();

        #pragma unroll
        for (int kk = 0; kk < BK; ++kk) {
            const float4 av = *reinterpret_cast<const float4*>(&As[kk][ty * 4]);
            const float4 bv = *reinterpret_cast<const float4*>(&Bs[kk][tx * 4]);
            const float a[4] = {av.x, av.y, av.z, av.w};
            const float b[4] = {bv.x, bv.y, bv.z, bv.w};
            #pragma unroll
            for (int i = 0; i < 4; ++i)
                #pragma unroll
                for (int j = 0; j < 4; ++j)
                    acc[i][j] = fmaf(a[i], b[j], acc[i][j]);
        }
        __syncthreads();
    }

    #pragma unroll
    for (int i = 0; i < 4; ++i) {
        int r = row0 + ty * 4 + i;
        #pragma unroll
        for (int j = 0; j < 4; ++j) {
            int c = col0 + tx * 4 + j;
            float v = acc[i][j];
            if (EPI == 1) v = softplus_f(v + aux[c]);
            if (EPI == 2) v = v + aux[(size_t)r * N + c];
            C[(size_t)r * N + c] = v;
        }
    }
}

// ---------------------------------------------------------------------------
// Causal depthwise conv(4) + bias + SiLU.
// Input: xz [MROWS, 2*DIN], uses first DIN columns. Output: xc [MROWS, DIN].
// ---------------------------------------------------------------------------
__global__ __launch_bounds__(256) void conv_silu(
    const float* __restrict__ xz, const float* __restrict__ Wc,
    const float* __restrict__ bc, float* __restrict__ xc)
{
    int idx = blockIdx.x * 256 + threadIdx.x;      // m*DIN + e
    int e = idx & (DIN - 1);
    int m = idx >> 11;
    int l = m & (LSEQ - 1);

    const float4 w = reinterpret_cast<const float4*>(Wc)[e];  // W_conv[e,0,0..3]
    float acc = bc[e];
    if (l >= 3) acc = fmaf(xz[(size_t)(m - 3) * (2 * DIN) + e], w.x, acc);
    if (l >= 2) acc = fmaf(xz[(size_t)(m - 2) * (2 * DIN) + e], w.y, acc);
    if (l >= 1) acc = fmaf(xz[(size_t)(m - 1) * (2 * DIN) + e], w.z, acc);
    acc = fmaf(xz[(size_t)m * (2 * DIN) + e], w.w, acc);
    // silu
    float s = acc / (1.0f + __expf(-acc));
    xc[idx] = s;
}

// ---------------------------------------------------------------------------
// B_t / C_t projections: per row m, 16+16 dot products of length DIN.
// ---------------------------------------------------------------------------
__global__ __launch_bounds__(256) void bc_proj(
    const float* __restrict__ xc, const float* __restrict__ WB,
    const float* __restrict__ WC, float* __restrict__ Bt, float* __restrict__ Ct)
{
    __shared__ float row[DIN];
    const int m = blockIdx.x;
    for (int i = threadIdx.x; i < DIN; i += 256)
        row[i] = xc[(size_t)m * DIN + i];
    __syncthreads();

    const int o   = threadIdx.x >> 3;  // 0..31
    const int sub = threadIdx.x & 7;
    const float* W = (o < DSTATE) ? (WB + (size_t)o * DIN) : (WC + (size_t)(o - DSTATE) * DIN);
    float p = 0.0f;
    for (int j = sub; j < DIN; j += 8)
        p = fmaf(row[j], W[j], p);
    p += __shfl_xor(p, 1, 8);
    p += __shfl_xor(p, 2, 8);
    p += __shfl_xor(p, 4, 8);
    if (sub == 0) {
        if (o < DSTATE) Bt[(size_t)m * DSTATE + o] = p;
        else            Ct[(size_t)m * DSTATE + (o - DSTATE)] = p;
    }
}

// ---------------------------------------------------------------------------
// Selective scan. 16 lanes per (b,e) channel = 16 states. 256 thr = 16 groups.
// yg[m,e] = (sum_s h*C + xc*D) * silu(z)
// ---------------------------------------------------------------------------
__global__ __launch_bounds__(256) void scan_kernel(
    const float* __restrict__ delta, const float* __restrict__ xc,
    const float* __restrict__ Bt, const float* __restrict__ Ct,
    const float* __restrict__ xz, const float* __restrict__ A_log,
    const float* __restrict__ Dv, float* __restrict__ yg)
{
    const int t      = threadIdx.x;
    const int lane_s = t & 15;          // state index
    const int g      = t >> 4;          // group in block
    const int ge     = blockIdx.x * 16 + g;   // 0..B*DIN-1
    const int b      = ge >> 11;        // / DIN
    const int e      = ge & (DIN - 1);

    const float Aval = -__expf(A_log[lane_s]);
    const float Dval = Dv[e];

    float h = 0.0f;
    const int mbase = b * LSEQ;
    for (int l = 0; l < LSEQ; ++l) {
        const int m = mbase + l;
        const float dv = delta[(size_t)m * DIN + e];
        const float xv = xc[(size_t)m * DIN + e];
        const float bv = Bt[(size_t)m * DSTATE + lane_s];
        const float cv = Ct[(size_t)m * DSTATE + lane_s];
        h = fmaf(h, __expf(dv * Aval), dv * bv * xv);
        float p = h * cv;
        p += __shfl_xor(p, 1, 16);
        p += __shfl_xor(p, 2, 16);
        p += __shfl_xor(p, 4, 16);
        p += __shfl_xor(p, 8, 16);
        if (lane_s == 0) {
            const float zv = xz[(size_t)m * (2 * DIN) + DIN + e];
            const float sz = zv / (1.0f + __expf(-zv));
            yg[(size_t)m * DIN + e] = (p + xv * Dval) * sz;
        }
    }
}

// ---------------------------------------------------------------------------
extern "C" void kernel_launch(void* const* d_in, const int* in_sizes, int n_in,
                              void* d_out, int out_size, void* d_ws, size_t ws_size,
                              hipStream_t stream)
{
    const float* x      = (const float*)d_in[0];
    const float* W_in   = (const float*)d_in[1];
    const float* W_conv = (const float*)d_in[2];
    const float* b_conv = (const float*)d_in[3];
    const float* W_dt   = (const float*)d_in[4];
    const float* b_dt   = (const float*)d_in[5];
    const float* W_B    = (const float*)d_in[6];
    const float* W_C    = (const float*)d_in[7];
    const float* A_log  = (const float*)d_in[8];
    const float* Dvec   = (const float*)d_in[9];
    const float* W_out  = (const float*)d_in[10];
    float* out = (float*)d_out;

    float* ws    = (float*)d_ws;
    float* xz    = ws;                                  // [2048, 4096]
    float* xc    = xz + (size_t)MROWS * 2 * DIN;        // [2048, 2048]
    float* delta = xc + (size_t)MROWS * DIN;            // [2048, 2048]
    float* Bt    = delta + (size_t)MROWS * DIN;         // [2048, 16]
    float* Ct    = Bt + (size_t)MROWS * DSTATE;         // [2048, 16]
    float* yg    = Ct + (size_t)MROWS * DSTATE;         // [2048, 2048]

    // 1. xz = x @ W_in^T        [2048, 4096] = [2048,1024] x [4096,1024]^T
    gemm_nt<0><<<dim3((2 * DIN) / BN, MROWS / BM), 256, 0, stream>>>(
        x, W_in, xz, MROWS, 2 * DIN, DIM, nullptr);

    // 2. causal conv + silu -> xc
    conv_silu<<<(MROWS * DIN) / 256, 256, 0, stream>>>(xz, W_conv, b_conv, xc);

    // 3. delta = softplus(xc @ W_dt^T + b_dt)
    gemm_nt<1><<<dim3(DIN / BN, MROWS / BM), 256, 0, stream>>>(
        xc, W_dt, delta, MROWS, DIN, DIN, b_dt);

    // 4. B_t, C_t projections
    bc_proj<<<MROWS, 256, 0, stream>>>(xc, W_B, W_C, Bt, Ct);

    // 5. selective scan + gating
    scan_kernel<<<(B_SZ * DIN) / 16, 256, 0, stream>>>(
        delta, xc, Bt, Ct, xz, A_log, Dvec, yg);

    // 6. out = x + yg @ W_out^T
    gemm_nt<2><<<dim3(DIM / BN, MROWS / BM), 256, 0, stream>>>(
        yg, W_out, out, MROWS, DIM, DIN, x);
}

// Round 2
// 760.112 us; speedup vs baseline: 1.8619x; 1.8619x over previous
//
#include <hip/hip_runtime.h>
#include <math.h>

// Problem constants (fixed by the reference)
#define B_SZ    2
#define LSEQ    1024
#define DIM     1024
#define DSTATE  16
#define DCONV   4
#define DIN     2048          // d_inner
#define MROWS   (B_SZ * LSEQ) // 2048
#define CH      (B_SZ * DIN)  // 4096 channels
#define NCHUNK  32
#define LC      (LSEQ / NCHUNK)  // 32

// ---------------------------------------------------------------------------
// NT GEMM: C[m,n] = sum_k A[m,k] * B[n,k]   (A row-major [M,K], B row-major [N,K])
// EPI: 0 = plain store; 1 = softplus(acc + aux[n]); 2 = acc + aux[m*N+n]
// Tile 64x64, 256 threads, 4x4 per thread, BK=16.
// ---------------------------------------------------------------------------
#define BM 64
#define BN 64
#define BK 16

__device__ __forceinline__ float softplus_f(float x) {
    return fmaxf(x, 0.0f) + log1pf(__expf(-fabsf(x)));
}

template <int EPI>
__global__ __launch_bounds__(256) void gemm_nt(
    const float* __restrict__ A, const float* __restrict__ Bm,
    float* __restrict__ C, int M, int N, int K,
    const float* __restrict__ aux)
{
    __shared__ float As[BK][BM + 4];
    __shared__ float Bs[BK][BN + 4];

    const int t   = threadIdx.x;
    const int tx  = t & 15;
    const int ty  = t >> 4;
    const int row0 = blockIdx.y * BM;
    const int col0 = blockIdx.x * BN;

    float acc[4][4] = {};

    for (int k0 = 0; k0 < K; k0 += BK) {
        #pragma unroll
        for (int i = 0; i < 4; ++i) {
            int idx = t + i * 256;
            int r   = idx >> 4;
            int kk  = idx & 15;
            As[kk][r] = A[(size_t)(row0 + r) * K + k0 + kk];
            Bs[kk][r] = Bm[(size_t)(col0 + r) * K + k0 + kk];
        }
        __syncthreads();

        #pragma unroll
        for (int kk = 0; kk < BK; ++kk) {
            const float4 av = *reinterpret_cast<const float4*>(&As[kk][ty * 4]);
            const float4 bv = *reinterpret_cast<const float4*>(&Bs[kk][tx * 4]);
            const float a[4] = {av.x, av.y, av.z, av.w};
            const float b[4] = {bv.x, bv.y, bv.z, bv.w};
            #pragma unroll
            for (int i = 0; i < 4; ++i)
                #pragma unroll
                for (int j = 0; j < 4; ++j)
                    acc[i][j] = fmaf(a[i], b[j], acc[i][j]);
        }
        __syncthreads();
    }

    #pragma unroll
    for (int i = 0; i < 4; ++i) {
        int r = row0 + ty * 4 + i;
        #pragma unroll
        for (int j = 0; j < 4; ++j) {
            int c = col0 + tx * 4 + j;
            float v = acc[i][j];
            if (EPI == 1) v = softplus_f(v + aux[c]);
            if (EPI == 2) v = v + aux[(size_t)r * N + c];
            C[(size_t)r * N + c] = v;
        }
    }
}

// ---------------------------------------------------------------------------
// Causal depthwise conv(4) + bias + SiLU.
// ---------------------------------------------------------------------------
__global__ __launch_bounds__(256) void conv_silu(
    const float* __restrict__ xz, const float* __restrict__ Wc,
    const float* __restrict__ bc, float* __restrict__ xc)
{
    int idx = blockIdx.x * 256 + threadIdx.x;      // m*DIN + e
    int e = idx & (DIN - 1);
    int m = idx >> 11;
    int l = m & (LSEQ - 1);

    const float4 w = reinterpret_cast<const float4*>(Wc)[e];
    float acc = bc[e];
    if (l >= 3) acc = fmaf(xz[(size_t)(m - 3) * (2 * DIN) + e], w.x, acc);
    if (l >= 2) acc = fmaf(xz[(size_t)(m - 2) * (2 * DIN) + e], w.y, acc);
    if (l >= 1) acc = fmaf(xz[(size_t)(m - 1) * (2 * DIN) + e], w.z, acc);
    acc = fmaf(xz[(size_t)m * (2 * DIN) + e], w.w, acc);
    float s = acc / (1.0f + __expf(-acc));
    xc[idx] = s;
}

// ---------------------------------------------------------------------------
// B_t / C_t projections.
// ---------------------------------------------------------------------------
__global__ __launch_bounds__(256) void bc_proj(
    const float* __restrict__ xc, const float* __restrict__ WB,
    const float* __restrict__ WC, float* __restrict__ Bt, float* __restrict__ Ct)
{
    __shared__ float row[DIN];
    const int m = blockIdx.x;
    for (int i = threadIdx.x; i < DIN; i += 256)
        row[i] = xc[(size_t)m * DIN + i];
    __syncthreads();

    const int o   = threadIdx.x >> 3;
    const int sub = threadIdx.x & 7;
    const float* W = (o < DSTATE) ? (WB + (size_t)o * DIN) : (WC + (size_t)(o - DSTATE) * DIN);
    float p = 0.0f;
    for (int j = sub; j < DIN; j += 8)
        p = fmaf(row[j], W[j], p);
    p += __shfl_xor(p, 1, 8);
    p += __shfl_xor(p, 2, 8);
    p += __shfl_xor(p, 4, 8);
    if (sub == 0) {
        if (o < DSTATE) Bt[(size_t)m * DSTATE + o] = p;
        else            Ct[(size_t)m * DSTATE + (o - DSTATE)] = p;
    }
}

// ---------------------------------------------------------------------------
// Chunked selective scan — pass 1: per-chunk local scan from h=0.
// One thread per channel; h[16] in registers. Stores final h + sum(delta).
// hfin layout: [CH, NCHUNK, 16]; dsums: [CH, NCHUNK]
// ---------------------------------------------------------------------------
__global__ __launch_bounds__(256) void scan_pass1(
    const float* __restrict__ delta, const float* __restrict__ xc,
    const float* __restrict__ Bt, const float* __restrict__ A_log,
    float* __restrict__ hfin, float* __restrict__ dsums)
{
    const int ge = blockIdx.x * 256 + threadIdx.x;   // channel 0..CH-1
    const int c  = blockIdx.y;                        // chunk
    const int b  = ge >> 11;
    const int e  = ge & (DIN - 1);

    float A[DSTATE];
    #pragma unroll
    for (int s = 0; s < DSTATE; ++s) A[s] = -__expf(A_log[s]);

    float h[DSTATE] = {};
    float dsum = 0.0f;
    const int m0 = b * LSEQ + c * LC;

    for (int l = 0; l < LC; ++l) {
        const int m = m0 + l;
        const float dv = delta[(size_t)m * DIN + e];
        const float xv = xc[(size_t)m * DIN + e];
        dsum += dv;
        const float dx = dv * xv;
        #pragma unroll
        for (int s = 0; s < DSTATE; ++s) {
            const float bv = Bt[(size_t)m * DSTATE + s];
            h[s] = fmaf(h[s], __expf(dv * A[s]), dx * bv);
        }
    }

    float4* hf = reinterpret_cast<float4*>(&hfin[((size_t)ge * NCHUNK + c) * DSTATE]);
    #pragma unroll
    for (int q = 0; q < 4; ++q)
        hf[q] = make_float4(h[4*q], h[4*q+1], h[4*q+2], h[4*q+3]);
    dsums[(size_t)ge * NCHUNK + c] = dsum;
}

// ---------------------------------------------------------------------------
// Pass 2: sequential combine over chunks (in place: hfin becomes carry-in).
// Thread t -> (ge = t>>4, s = t&15).
// ---------------------------------------------------------------------------
__global__ __launch_bounds__(256) void scan_pass2(
    float* __restrict__ hfin, const float* __restrict__ dsums,
    const float* __restrict__ A_log)
{
    const int t  = blockIdx.x * 256 + threadIdx.x;   // 0..CH*DSTATE-1
    const int ge = t >> 4;
    const int s  = t & 15;
    const float A = -__expf(A_log[s]);

    float h = 0.0f;
    for (int c = 0; c < NCHUNK; ++c) {
        const size_t idx = ((size_t)ge * NCHUNK + c) * DSTATE + s;
        const float hf = hfin[idx];                  // local final of chunk c
        hfin[idx] = h;                               // overwrite with carry-IN of chunk c
        const float P = __expf(A * dsums[(size_t)ge * NCHUNK + c]);
        h = fmaf(P, h, hf);
    }
}

// ---------------------------------------------------------------------------
// Pass 3: re-run local scan seeded with carry-in; fuse C-dot, D, silu(z) gate.
// yg may alias delta (each [m,e] read once by the same thread that writes it).
// ---------------------------------------------------------------------------
__global__ __launch_bounds__(256) void scan_pass3(
    const float* __restrict__ delta, const float* __restrict__ xc,
    const float* __restrict__ Bt, const float* __restrict__ Ct,
    const float* __restrict__ xz, const float* __restrict__ A_log,
    const float* __restrict__ Dv, const float* __restrict__ hcar,
    float* __restrict__ yg)
{
    const int ge = blockIdx.x * 256 + threadIdx.x;
    const int c  = blockIdx.y;
    const int b  = ge >> 11;
    const int e  = ge & (DIN - 1);

    float A[DSTATE];
    #pragma unroll
    for (int s = 0; s < DSTATE; ++s) A[s] = -__expf(A_log[s]);

    float h[DSTATE];
    const float4* hc = reinterpret_cast<const float4*>(&hcar[((size_t)ge * NCHUNK + c) * DSTATE]);
    #pragma unroll
    for (int q = 0; q < 4; ++q) {
        const float4 v = hc[q];
        h[4*q]   = v.x; h[4*q+1] = v.y; h[4*q+2] = v.z; h[4*q+3] = v.w;
    }

    const float Dval = Dv[e];
    const int m0 = b * LSEQ + c * LC;

    for (int l = 0; l < LC; ++l) {
        const int m = m0 + l;
        const float dv = delta[(size_t)m * DIN + e];
        const float xv = xc[(size_t)m * DIN + e];
        const float dx = dv * xv;
        float y = xv * Dval;
        #pragma unroll
        for (int s = 0; s < DSTATE; ++s) {
            const float bv = Bt[(size_t)m * DSTATE + s];
            const float cv = Ct[(size_t)m * DSTATE + s];
            h[s] = fmaf(h[s], __expf(dv * A[s]), dx * bv);
            y = fmaf(h[s], cv, y);
        }
        const float zv = xz[(size_t)m * (2 * DIN) + DIN + e];
        const float sz = zv / (1.0f + __expf(-zv));
        yg[(size_t)m * DIN + e] = y * sz;
    }
}

// ---------------------------------------------------------------------------
extern "C" void kernel_launch(void* const* d_in, const int* in_sizes, int n_in,
                              void* d_out, int out_size, void* d_ws, size_t ws_size,
                              hipStream_t stream)
{
    const float* x      = (const float*)d_in[0];
    const float* W_in   = (const float*)d_in[1];
    const float* W_conv = (const float*)d_in[2];
    const float* b_conv = (const float*)d_in[3];
    const float* W_dt   = (const float*)d_in[4];
    const float* b_dt   = (const float*)d_in[5];
    const float* W_B    = (const float*)d_in[6];
    const float* W_C    = (const float*)d_in[7];
    const float* A_log  = (const float*)d_in[8];
    const float* Dvec   = (const float*)d_in[9];
    const float* W_out  = (const float*)d_in[10];
    float* out = (float*)d_out;

    float* ws    = (float*)d_ws;
    float* xz    = ws;                                  // [2048, 4096]
    float* xc    = xz + (size_t)MROWS * 2 * DIN;        // [2048, 2048]
    float* delta = xc + (size_t)MROWS * DIN;            // [2048, 2048] (aliased by yg)
    float* Bt    = delta + (size_t)MROWS * DIN;         // [2048, 16]
    float* Ct    = Bt + (size_t)MROWS * DSTATE;         // [2048, 16]
    float* hfin  = Ct + (size_t)MROWS * DSTATE;         // [CH, NCHUNK, 16]
    float* dsums = hfin + (size_t)CH * NCHUNK * DSTATE; // [CH, NCHUNK]
    float* yg    = delta;                               // alias (safe: see pass 3)

    // 1. xz = x @ W_in^T
    gemm_nt<0><<<dim3((2 * DIN) / BN, MROWS / BM), 256, 0, stream>>>(
        x, W_in, xz, MROWS, 2 * DIN, DIM, nullptr);

    // 2. causal conv + silu -> xc
    conv_silu<<<(MROWS * DIN) / 256, 256, 0, stream>>>(xz, W_conv, b_conv, xc);

    // 3. delta = softplus(xc @ W_dt^T + b_dt)
    gemm_nt<1><<<dim3(DIN / BN, MROWS / BM), 256, 0, stream>>>(
        xc, W_dt, delta, MROWS, DIN, DIN, b_dt);

    // 4. B_t, C_t projections
    bc_proj<<<MROWS, 256, 0, stream>>>(xc, W_B, W_C, Bt, Ct);

    // 5. chunked selective scan
    scan_pass1<<<dim3(CH / 256, NCHUNK), 256, 0, stream>>>(
        delta, xc, Bt, A_log, hfin, dsums);
    scan_pass2<<<(CH * DSTATE) / 256, 256, 0, stream>>>(hfin, dsums, A_log);
    scan_pass3<<<dim3(CH / 256, NCHUNK), 256, 0, stream>>>(
        delta, xc, Bt, Ct, xz, A_log, Dvec, hfin, yg);

    // 6. out = x + yg @ W_out^T
    gemm_nt<2><<<dim3(DIM / BN, MROWS / BM), 256, 0, stream>>>(
        yg, W_out, out, MROWS, DIM, DIN, x);
}

// Round 4
// 271.758 us; speedup vs baseline: 5.2077x; 2.7970x over previous
//
#include <hip/hip_runtime.h>
#include <math.h>

// Problem constants (fixed by the reference)
#define B_SZ    2
#define LSEQ    1024
#define DIM     1024
#define DSTATE  16
#define DCONV   4
#define DIN     2048          // d_inner
#define MROWS   (B_SZ * LSEQ) // 2048
#define CH      (B_SZ * DIN)  // 4096 channels
#define NCHUNK  32
#define LC      (LSEQ / NCHUNK)  // 32

typedef short  bf16x8 __attribute__((ext_vector_type(8)));
typedef float  f32x4  __attribute__((ext_vector_type(4)));

__device__ __forceinline__ float softplus_f(float x) {
    return fmaxf(x, 0.0f) + log1pf(__expf(-fabsf(x)));
}

__device__ __forceinline__ unsigned short f2bf(float x) {
    unsigned u = __float_as_uint(x);
    u = (u + 0x7FFF + ((u >> 16) & 1)) >> 16;
    return (unsigned short)u;
}

__device__ __forceinline__ float bf2f(unsigned short u) {
    return __uint_as_float((unsigned)u << 16);
}

__device__ __forceinline__ void load_lds16(const void* g, void* l) {
    __builtin_amdgcn_global_load_lds(
        (const __attribute__((address_space(1))) unsigned int*)g,
        (__attribute__((address_space(3))) unsigned int*)l, 16, 0, 0);
}

// ---------------------------------------------------------------------------
// f32 -> bf16 conversion (vectorized, 4 elems/thread)
// ---------------------------------------------------------------------------
__global__ __launch_bounds__(256) void f32_to_bf16(
    const float* __restrict__ src, unsigned short* __restrict__ dst, int n)
{
    int i = (blockIdx.x * 256 + threadIdx.x) * 4;
    if (i >= n) return;
    const float4 v = *reinterpret_cast<const float4*>(src + i);
    ushort4 o;
    o.x = f2bf(v.x); o.y = f2bf(v.y); o.z = f2bf(v.z); o.w = f2bf(v.w);
    *reinterpret_cast<ushort4*>(dst + i) = o;
}

// ---------------------------------------------------------------------------
// bf16 MFMA NT GEMM: C[m,n] = sum_k A[m,k]*B[n,k], fp32 out.
// 128x128 tile, BK=32, 256 thr = 4 waves (2x2), 4x4 16x16x32 frags per wave.
// Staging: global_load_lds width=16, linear LDS [128][32] bf16 (8 KB each).
// EPI: 0 plain; 1 softplus(acc+aux[n]); 2 acc+aux[m*N+n]
// ---------------------------------------------------------------------------
template <int EPI>
__global__ __launch_bounds__(256) void gemm_bf16(
    const unsigned short* __restrict__ A, const unsigned short* __restrict__ Bm,
    float* __restrict__ C, int M, int N, int K,
    const float* __restrict__ aux)
{
    __shared__ unsigned short As[128 * 32];
    __shared__ unsigned short Bs[128 * 32];

    const int t    = threadIdx.x;
    const int lane = t & 63;
    const int w    = t >> 6;          // wave 0..3
    const int wr   = w >> 1;          // wave row (0..1)
    const int wc   = w & 1;           // wave col (0..1)
    const int row0 = blockIdx.y * 128;
    const int col0 = blockIdx.x * 128;

    const int lrow  = lane & 15;      // fragment row
    const int kslot = lane >> 4;      // 0..3 (k-group of 8)

    f32x4 acc[4][4];
    #pragma unroll
    for (int i = 0; i < 4; ++i)
        #pragma unroll
        for (int j = 0; j < 4; ++j)
            acc[i][j] = (f32x4){0.f, 0.f, 0.f, 0.f};

    for (int k0 = 0; k0 < K; k0 += 32) {
        // stage A-tile and B-tile: 8192 B each = 2 chunks of 256x16 B
        #pragma unroll
        for (int p = 0; p < 2; ++p) {
            const int o    = t + p * 256;        // 16-byte unit index 0..511
            const int row  = o >> 2;             // 0..127
            const int slot = o & 3;              // 16B slot within 64B row
            char* lbase_a = (char*)As + p * 4096 + w * 1024;   // wave-uniform
            char* lbase_b = (char*)Bs + p * 4096 + w * 1024;
            load_lds16(A  + (size_t)(row0 + row) * K + k0 + slot * 8, lbase_a);
            load_lds16(Bm + (size_t)(col0 + row) * K + k0 + slot * 8, lbase_b);
        }
        __syncthreads();

        bf16x8 af[4], bf[4];
        #pragma unroll
        for (int i = 0; i < 4; ++i) {
            af[i] = *reinterpret_cast<const bf16x8*>(&As[(wr * 64 + i * 16 + lrow) * 32 + kslot * 8]);
            bf[i] = *reinterpret_cast<const bf16x8*>(&Bs[(wc * 64 + i * 16 + lrow) * 32 + kslot * 8]);
        }
        #pragma unroll
        for (int i = 0; i < 4; ++i)
            #pragma unroll
            for (int j = 0; j < 4; ++j)
                acc[i][j] = __builtin_amdgcn_mfma_f32_16x16x32_bf16(af[i], bf[j], acc[i][j], 0, 0, 0);
        __syncthreads();
    }

    // epilogue: D mapping col=lane&15, row=(lane>>4)*4+q
    #pragma unroll
    for (int i = 0; i < 4; ++i) {
        const int r0 = row0 + wr * 64 + i * 16 + (lane >> 4) * 4;
        #pragma unroll
        for (int j = 0; j < 4; ++j) {
            const int c = col0 + wc * 64 + j * 16 + (lane & 15);
            #pragma unroll
            for (int q = 0; q < 4; ++q) {
                const int r = r0 + q;
                float v = acc[i][j][q];
                if (EPI == 1) v = softplus_f(v + aux[c]);
                if (EPI == 2) v = v + aux[(size_t)r * N + c];
                C[(size_t)r * N + c] = v;
            }
        }
    }
}

// ---------------------------------------------------------------------------
// Causal depthwise conv(4) + bias + SiLU -> bf16 xcb.
// ---------------------------------------------------------------------------
__global__ __launch_bounds__(256) void conv_silu(
    const float* __restrict__ xz, const float* __restrict__ Wc,
    const float* __restrict__ bc, unsigned short* __restrict__ xcb)
{
    int idx = blockIdx.x * 256 + threadIdx.x;      // m*DIN + e
    int e = idx & (DIN - 1);
    int m = idx >> 11;
    int l = m & (LSEQ - 1);

    const float4 w = reinterpret_cast<const float4*>(Wc)[e];
    float acc = bc[e];
    if (l >= 3) acc = fmaf(xz[(size_t)(m - 3) * (2 * DIN) + e], w.x, acc);
    if (l >= 2) acc = fmaf(xz[(size_t)(m - 2) * (2 * DIN) + e], w.y, acc);
    if (l >= 1) acc = fmaf(xz[(size_t)(m - 1) * (2 * DIN) + e], w.z, acc);
    acc = fmaf(xz[(size_t)m * (2 * DIN) + e], w.w, acc);
    float s = acc / (1.0f + __expf(-acc));
    xcb[idx] = f2bf(s);
}

// ---------------------------------------------------------------------------
// B_t / C_t projections (reads bf16 xcb, fp32 accumulate).
// ---------------------------------------------------------------------------
__global__ __launch_bounds__(256) void bc_proj(
    const unsigned short* __restrict__ xcb, const float* __restrict__ WB,
    const float* __restrict__ WC, float* __restrict__ Bt, float* __restrict__ Ct)
{
    __shared__ float row[DIN];
    const int m = blockIdx.x;
    for (int i = threadIdx.x; i < DIN; i += 256)
        row[i] = bf2f(xcb[(size_t)m * DIN + i]);
    __syncthreads();

    const int o   = threadIdx.x >> 3;
    const int sub = threadIdx.x & 7;
    const float* W = (o < DSTATE) ? (WB + (size_t)o * DIN) : (WC + (size_t)(o - DSTATE) * DIN);
    float p = 0.0f;
    for (int j = sub; j < DIN; j += 8)
        p = fmaf(row[j], W[j], p);
    p += __shfl_xor(p, 1, 8);
    p += __shfl_xor(p, 2, 8);
    p += __shfl_xor(p, 4, 8);
    if (sub == 0) {
        if (o < DSTATE) Bt[(size_t)m * DSTATE + o] = p;
        else            Ct[(size_t)m * DSTATE + (o - DSTATE)] = p;
    }
}

// ---------------------------------------------------------------------------
// Chunked selective scan — pass 1: per-chunk local scan from h=0.
// ---------------------------------------------------------------------------
__global__ __launch_bounds__(256) void scan_pass1(
    const float* __restrict__ delta, const unsigned short* __restrict__ xcb,
    const float* __restrict__ Bt, const float* __restrict__ A_log,
    float* __restrict__ hfin, float* __restrict__ dsums)
{
    const int ge = blockIdx.x * 256 + threadIdx.x;
    const int c  = blockIdx.y;
    const int b  = ge >> 11;
    const int e  = ge & (DIN - 1);

    float A[DSTATE];
    #pragma unroll
    for (int s = 0; s < DSTATE; ++s) A[s] = -__expf(A_log[s]);

    float h[DSTATE] = {};
    float dsum = 0.0f;
    const int m0 = b * LSEQ + c * LC;

    for (int l = 0; l < LC; ++l) {
        const int m = m0 + l;
        const float dv = delta[(size_t)m * DIN + e];
        const float xv = bf2f(xcb[(size_t)m * DIN + e]);
        dsum += dv;
        const float dx = dv * xv;
        #pragma unroll
        for (int s = 0; s < DSTATE; ++s) {
            const float bv = Bt[(size_t)m * DSTATE + s];
            h[s] = fmaf(h[s], __expf(dv * A[s]), dx * bv);
        }
    }

    float4* hf = reinterpret_cast<float4*>(&hfin[((size_t)ge * NCHUNK + c) * DSTATE]);
    #pragma unroll
    for (int q = 0; q < 4; ++q)
        hf[q] = make_float4(h[4*q], h[4*q+1], h[4*q+2], h[4*q+3]);
    dsums[(size_t)ge * NCHUNK + c] = dsum;
}

// ---------------------------------------------------------------------------
// Pass 2: sequential combine over chunks (in place).
// ---------------------------------------------------------------------------
__global__ __launch_bounds__(256) void scan_pass2(
    float* __restrict__ hfin, const float* __restrict__ dsums,
    const float* __restrict__ A_log)
{
    const int t  = blockIdx.x * 256 + threadIdx.x;
    const int ge = t >> 4;
    const int s  = t & 15;
    const float A = -__expf(A_log[s]);

    float h = 0.0f;
    for (int c = 0; c < NCHUNK; ++c) {
        const size_t idx = ((size_t)ge * NCHUNK + c) * DSTATE + s;
        const float hf = hfin[idx];
        hfin[idx] = h;
        const float P = __expf(A * dsums[(size_t)ge * NCHUNK + c]);
        h = fmaf(P, h, hf);
    }
}

// ---------------------------------------------------------------------------
// Pass 3: re-run local scan with carry-in; fuse C-dot, D, silu(z); bf16 out.
// ---------------------------------------------------------------------------
__global__ __launch_bounds__(256) void scan_pass3(
    const float* __restrict__ delta, const unsigned short* __restrict__ xcb,
    const float* __restrict__ Bt, const float* __restrict__ Ct,
    const float* __restrict__ xz, const float* __restrict__ A_log,
    const float* __restrict__ Dv, const float* __restrict__ hcar,
    unsigned short* __restrict__ ygb)
{
    const int ge = blockIdx.x * 256 + threadIdx.x;
    const int c  = blockIdx.y;
    const int b  = ge >> 11;
    const int e  = ge & (DIN - 1);

    float A[DSTATE];
    #pragma unroll
    for (int s = 0; s < DSTATE; ++s) A[s] = -__expf(A_log[s]);

    float h[DSTATE];
    const float4* hc = reinterpret_cast<const float4*>(&hcar[((size_t)ge * NCHUNK + c) * DSTATE]);
    #pragma unroll
    for (int q = 0; q < 4; ++q) {
        const float4 v = hc[q];
        h[4*q]   = v.x; h[4*q+1] = v.y; h[4*q+2] = v.z; h[4*q+3] = v.w;
    }

    const float Dval = Dv[e];
    const int m0 = b * LSEQ + c * LC;

    for (int l = 0; l < LC; ++l) {
        const int m = m0 + l;
        const float dv = delta[(size_t)m * DIN + e];
        const float xv = bf2f(xcb[(size_t)m * DIN + e]);
        const float dx = dv * xv;
        float y = xv * Dval;
        #pragma unroll
        for (int s = 0; s < DSTATE; ++s) {
            const float bv = Bt[(size_t)m * DSTATE + s];
            const float cv = Ct[(size_t)m * DSTATE + s];
            h[s] = fmaf(h[s], __expf(dv * A[s]), dx * bv);
            y = fmaf(h[s], cv, y);
        }
        const float zv = xz[(size_t)m * (2 * DIN) + DIN + e];
        const float sz = zv / (1.0f + __expf(-zv));
        ygb[(size_t)m * DIN + e] = f2bf(y * sz);
    }
}

// ---------------------------------------------------------------------------
extern "C" void kernel_launch(void* const* d_in, const int* in_sizes, int n_in,
                              void* d_out, int out_size, void* d_ws, size_t ws_size,
                              hipStream_t stream)
{
    const float* x      = (const float*)d_in[0];
    const float* W_in   = (const float*)d_in[1];
    const float* W_conv = (const float*)d_in[2];
    const float* b_conv = (const float*)d_in[3];
    const float* W_dt   = (const float*)d_in[4];
    const float* b_dt   = (const float*)d_in[5];
    const float* W_B    = (const float*)d_in[6];
    const float* W_C    = (const float*)d_in[7];
    const float* A_log  = (const float*)d_in[8];
    const float* Dvec   = (const float*)d_in[9];
    const float* W_out  = (const float*)d_in[10];
    float* out = (float*)d_out;

    // Workspace layout (84.75 MB total):
    float* ws    = (float*)d_ws;
    float* xz    = ws;                                  // [2048,4096] f32  32 MB
    float* delta = xz + (size_t)MROWS * 2 * DIN;        // [2048,2048] f32  16 MB
    float* Bt    = delta + (size_t)MROWS * DIN;         // [2048,16]   f32
    float* Ct    = Bt + (size_t)MROWS * DSTATE;         // [2048,16]   f32
    float* hfin  = Ct + (size_t)MROWS * DSTATE;         // [4096,32,16] f32  8 MB
    float* dsums = hfin + (size_t)CH * NCHUNK * DSTATE; // [4096,32]   f32  0.5 MB
    unsigned short* xb   = (unsigned short*)(dsums + (size_t)CH * NCHUNK); // [2048,1024] bf16 4 MB
    unsigned short* wbuf = xb + (size_t)MROWS * DIM;        // up to 4M bf16   8 MB
    unsigned short* xcb  = wbuf + (size_t)4 * 1024 * 1024;  // [2048,2048] bf16 8 MB
    unsigned short* ygb  = xcb + (size_t)MROWS * DIN;       // [2048,2048] bf16 8 MB  (own region!)

    // 1. convert x and W_in; xz = x @ W_in^T   [2048,4096], K=1024
    f32_to_bf16<<<(MROWS * DIM) / 1024, 256, 0, stream>>>(x, xb, MROWS * DIM);
    f32_to_bf16<<<(2 * DIN * DIM) / 1024, 256, 0, stream>>>(W_in, wbuf, 2 * DIN * DIM);
    gemm_bf16<0><<<dim3((2 * DIN) / 128, MROWS / 128), 256, 0, stream>>>(
        xb, wbuf, xz, MROWS, 2 * DIN, DIM, nullptr);

    // 2. causal conv + silu -> xcb (bf16)
    conv_silu<<<(MROWS * DIN) / 256, 256, 0, stream>>>(xz, W_conv, b_conv, xcb);

    // 3. delta = softplus(xcb @ W_dt^T + b_dt)  [2048,2048], K=2048
    f32_to_bf16<<<(DIN * DIN) / 1024, 256, 0, stream>>>(W_dt, wbuf, DIN * DIN);
    gemm_bf16<1><<<dim3(DIN / 128, MROWS / 128), 256, 0, stream>>>(
        xcb, wbuf, delta, MROWS, DIN, DIN, b_dt);

    // 4. B_t, C_t projections
    bc_proj<<<MROWS, 256, 0, stream>>>(xcb, W_B, W_C, Bt, Ct);

    // 5. chunked selective scan -> ygb (bf16)
    scan_pass1<<<dim3(CH / 256, NCHUNK), 256, 0, stream>>>(
        delta, xcb, Bt, A_log, hfin, dsums);
    scan_pass2<<<(CH * DSTATE) / 256, 256, 0, stream>>>(hfin, dsums, A_log);
    scan_pass3<<<dim3(CH / 256, NCHUNK), 256, 0, stream>>>(
        delta, xcb, Bt, Ct, xz, A_log, Dvec, hfin, ygb);

    // 6. out = x + ygb @ W_out^T  [2048,1024], K=2048
    f32_to_bf16<<<(DIM * DIN) / 1024, 256, 0, stream>>>(W_out, wbuf, DIM * DIN);
    gemm_bf16<2><<<dim3(DIM / 128, MROWS / 128), 256, 0, stream>>>(
        ygb, wbuf, out, MROWS, DIM, DIN, x);
}